// Round 3
// baseline (663.978 us; speedup 1.0000x reference)
//
#include <hip/hip_runtime.h>

// WaveCell v3: 2D staggered-grid elastic FDTD timestep, fused single kernel.
// B=4, NZ=NX=2048, fp32, periodic wrap (pow2 dims).
//
// v2 (620us harness / 212us dispatch): VALUBusy 8.7% (issue-bound fixed),
// BW 3.85 TB/s = 61% of achievable, FETCH 470MB vs 384MB ideal input.
// Diagnosis: (1) z-halo rows re-fetched per XCD (round-robin dispatch puts
// adjacent-z blocks on different private L2s); (2) shot loop at unroll 1
// serializes load-burst/drain/compute per shot -> latency under-covered.
//
// v3: (a) XCD-band blockIdx swizzle: xcd = bid&7, new = xcd*512 + bid>>3.
//     4096 blocks % 8 == 0 -> bijective. Each XCD owns a contiguous 256-row
//     z-band; halo working set ~2.6MB fits its 4MB L2.
//     (b) #pragma unroll 2 on the shot loop for cross-shot MLP.

constexpr int NZ = 2048;
constexpr int NX = 2048;
constexpr int B  = 4;
constexpr int PLANE = NZ * NX;      // 4,194,304
constexpr int VOL   = B * PLANE;    // 16,777,216
constexpr float DT    = 1e-3f;
constexpr float INV_H = 0.1f;       // 1/10m
constexpr int NBLK  = (PLANE / 4) / 256;   // 4096
constexpr int NXCD  = 8;
constexpr int BLK_PER_XCD = NBLK / NXCD;   // 512

typedef float f32x4 __attribute__((ext_vector_type(4)));

__device__ __forceinline__ float rcpf(float x) { return __builtin_amdgcn_rcpf(x); }
__device__ __forceinline__ float4 ld4(const float* __restrict__ p) {
    return *reinterpret_cast<const float4*>(p);
}
__device__ __forceinline__ void st_nt4(float* __restrict__ p,
                                       float a, float b, float c, float d) {
    f32x4 v = {a, b, c, d};
    __builtin_nontemporal_store(v, reinterpret_cast<f32x4*>(p));
}

__global__ __launch_bounds__(256) void wave_fused_v3(
    const float* __restrict__ vp,  const float* __restrict__ vs,
    const float* __restrict__ rho,
    const float* __restrict__ vx,  const float* __restrict__ vz,
    const float* __restrict__ txx, const float* __restrict__ tzz,
    const float* __restrict__ txz,
    const float* __restrict__ dd,
    float* __restrict__ out)
{
    // XCD-band swizzle: consecutive hardware dispatch slots round-robin the
    // 8 XCDs; give XCD k the contiguous block range [k*512, (k+1)*512) so
    // each XCD streams a contiguous 256-row z-band through its private L2.
    const int bid = blockIdx.x;
    const int sb  = (bid & (NXCD - 1)) * BLK_PER_XCD + (bid >> 3);
    const int t   = sb * blockDim.x + threadIdx.x;          // [0, PLANE/4)
    const int xg = (t & (NX / 4 - 1)) << 2;                 // x base, %4==0
    const int z  = t >> 9;                                  // t / (NX/4)
    const int zp = (z + 1) & (NZ - 1);
    const int zm = (z - 1) & (NZ - 1);
    const int xm1 = (xg - 1) & (NX - 1);
    const int xp4 = (xg + 4) & (NX - 1);
    const int rz  = z  * NX;
    const int rzp = zp * NX;
    const int rzm = zm * NX;

    // ---------- 2D coefficient setup (amortized over B=4 shots) ----------
    float dz6[6], rz6[6];
    {
        const float4 d4 = ld4(dd + rz + xg);
        dz6[0] = dd[rz + xm1]; dz6[1] = d4.x; dz6[2] = d4.y;
        dz6[3] = d4.z;         dz6[4] = d4.w; dz6[5] = dd[rz + xp4];
        const float4 r4 = ld4(rho + rz + xg);
        rz6[0] = rho[rz + xm1]; rz6[1] = r4.x; rz6[2] = r4.y;
        rz6[3] = r4.z;          rz6[4] = r4.w; rz6[5] = rho[rz + xp4];
    }
    float avz[6], bvz[6], inv_c[4];
    #pragma unroll
    for (int j = 0; j < 6; ++j) {
        const float c   = 0.5f * DT * dz6[j];
        const float inv = rcpf(1.0f + c);
        avz[j] = (1.0f - c) * inv;
        bvz[j] = DT * INV_H * inv * rcpf(rz6[j]);
        if (j >= 1 && j <= 4) inv_c[j - 1] = inv;   // static after unroll
    }
    float avzp[4], bvzp[4], avzm[4], bvzm[4];
    {
        const float4 dp = ld4(dd + rzp + xg), dm = ld4(dd + rzm + xg);
        const float4 rp = ld4(rho + rzp + xg), rm = ld4(rho + rzm + xg);
        const float dpa[4] = {dp.x, dp.y, dp.z, dp.w};
        const float dma[4] = {dm.x, dm.y, dm.z, dm.w};
        const float rpa[4] = {rp.x, rp.y, rp.z, rp.w};
        const float rma[4] = {rm.x, rm.y, rm.z, rm.w};
        #pragma unroll
        for (int k = 0; k < 4; ++k) {
            float c = 0.5f * DT * dpa[k];
            float inv = rcpf(1.0f + c);
            avzp[k] = (1.0f - c) * inv;
            bvzp[k] = DT * INV_H * inv * rcpf(rpa[k]);
            c = 0.5f * DT * dma[k];
            inv = rcpf(1.0f + c);
            avzm[k] = (1.0f - c) * inv;
            bvzm[k] = DT * INV_H * inv * rcpf(rma[k]);
        }
    }
    float q1[4], q2[4], q3[4], a_s[4];
    {
        const float4 vp4 = ld4(vp + rz + xg), vs4 = ld4(vs + rz + xg);
        const float vpa[4] = {vp4.x, vp4.y, vp4.z, vp4.w};
        const float vsa[4] = {vs4.x, vs4.y, vs4.z, vs4.w};
        #pragma unroll
        for (int k = 0; k < 4; ++k) {
            const float r   = rz6[k + 1];
            const float muv = r * vsa[k] * vsa[k];
            const float lam = r * vpa[k] * vpa[k] - 2.0f * muv;
            const float bsH = DT * INV_H * inv_c[k];
            q1[k] = bsH * (lam + 2.0f * muv);
            q2[k] = bsH * lam;
            q3[k] = bsH * muv;
            a_s[k] = avz[k + 1];
        }
    }

    // ---------- per-shot field update ----------
    #pragma unroll 2   // 2 shots in flight: cross-shot MLP, bounded VGPR
    for (int b = 0; b < B; ++b) {
        const int b3  = b * PLANE;
        const int cz  = b3 + rz  + xg;
        const int czp = b3 + rzp + xg;
        const int czm = b3 + rzm + xg;

        // row segments (array index j <-> column xg-1+j unless noted)
        float txxz[6], txzz[6], tzzz[5], tzzzp[5], txxzp[5];
        float txzzm[5];                 // index k <-> column xg+k
        float vxz[5];                   // index k <-> column xg+k
        float vzz[5];                   // index j <-> column xg-1+j
        {
            float4 m;
            m = ld4(txx + cz);
            txxz[1] = m.x; txxz[2] = m.y; txxz[3] = m.z; txxz[4] = m.w;
            txxz[0] = txx[b3 + rz + xm1];  txxz[5] = txx[b3 + rz + xp4];
            m = ld4(txz + cz);
            txzz[1] = m.x; txzz[2] = m.y; txzz[3] = m.z; txzz[4] = m.w;
            txzz[0] = txz[b3 + rz + xm1];  txzz[5] = txz[b3 + rz + xp4];
            m = ld4(tzz + cz);
            tzzz[1] = m.x; tzzz[2] = m.y; tzzz[3] = m.z; tzzz[4] = m.w;
            tzzz[0] = tzz[b3 + rz + xm1];
            m = ld4(tzz + czp);
            tzzzp[1] = m.x; tzzzp[2] = m.y; tzzzp[3] = m.z; tzzzp[4] = m.w;
            tzzzp[0] = tzz[b3 + rzp + xm1];
            m = ld4(txx + czp);
            txxzp[1] = m.x; txxzp[2] = m.y; txxzp[3] = m.z; txxzp[4] = m.w;
            txxzp[0] = txx[b3 + rzp + xm1];
            m = ld4(txz + czm);
            txzzm[0] = m.x; txzzm[1] = m.y; txzzm[2] = m.z; txzzm[3] = m.w;
            txzzm[4] = txz[b3 + rzm + xp4];
            m = ld4(vx + cz);
            vxz[0] = m.x; vxz[1] = m.y; vxz[2] = m.z; vxz[3] = m.w;
            vxz[4] = vx[b3 + rz + xp4];
            m = ld4(vz + cz);
            vzz[1] = m.x; vzz[2] = m.y; vzz[3] = m.z; vzz[4] = m.w;
            vzz[0] = vz[b3 + rz + xm1];
        }
        const float4 tp4 = ld4(txz + czp);   // txz row zp, cols xg..xg+3
        const float4 tm4 = ld4(tzz + czm);   // tzz row zm, cols xg..xg+3
        const float4 vxp4 = ld4(vx + czp);   // vx  row zp, cols xg..xg+3
        const float4 vzm4 = ld4(vz + czm);   // vz  row zm, cols xg..xg+3
        const float txzzp[4] = {tp4.x, tp4.y, tp4.z, tp4.w};
        const float tzzzm[4] = {tm4.x, tm4.y, tm4.z, tm4.w};
        const float vxzp[4]  = {vxp4.x, vxp4.y, vxp4.z, vxp4.w};
        const float vzzm[4]  = {vzm4.x, vzm4.y, vzm4.z, vzm4.w};

        // --- new velocities (leapfrog: from old stresses) ---
        float vxn_z[5];                 // vx_new(z, xg+k), k=0..4
        #pragma unroll
        for (int k = 0; k < 5; ++k)
            vxn_z[k] = avz[k + 1] * vxz[k]
                     + bvz[k + 1] * ((txxz[k + 1] - txxz[k])
                                   + (txzz[k + 1] - txzzm[k]));
        float vzn_z[5];                 // vz_new(z, xg-1+k), k=0..4
        #pragma unroll
        for (int k = 0; k < 5; ++k)
            vzn_z[k] = avz[k] * vzz[k]
                     + bvz[k] * ((txzz[k + 1] - txzz[k])
                               + (tzzzp[k] - tzzz[k]));
        float vxn_zp[4];                // vx_new(zp, xg+k)
        #pragma unroll
        for (int k = 0; k < 4; ++k)
            vxn_zp[k] = avzp[k] * vxzp[k]
                      + bvzp[k] * ((txxzp[k + 1] - txxzp[k])
                                 + (txzzp[k] - txzz[k + 1]));
        float vzn_zm[4];                // vz_new(zm, xg+k)
        #pragma unroll
        for (int k = 0; k < 4; ++k)
            vzn_zm[k] = avzm[k] * vzzm[k]
                      + bvzm[k] * ((txzzm[k + 1] - txzzm[k])
                                 + (tzzz[k + 1] - tzzzm[k]));

        // --- stress update (from new velocities) ---
        float oxx[4], ozz[4], oxz[4];
        #pragma unroll
        for (int k = 0; k < 4; ++k) {
            const float dvx = vxn_z[k + 1] - vxn_z[k];          // d+x vx_new
            const float dvz = vzn_z[k + 1] - vzn_zm[k];         // d-z vz_new
            oxx[k] = a_s[k] * txxz[k + 1] + q1[k] * dvx + q2[k] * dvz;
            ozz[k] = a_s[k] * tzzz[k + 1] + q1[k] * dvz + q2[k] * dvx;
            oxz[k] = a_s[k] * txzz[k + 1]
                   + q3[k] * ((vxn_zp[k] - vxn_z[k])
                            + (vzn_z[k + 1] - vzn_z[k]));
        }

        st_nt4(out + 0 * VOL + cz, vxn_z[0], vxn_z[1], vxn_z[2], vxn_z[3]);
        st_nt4(out + 1 * VOL + cz, vzn_z[1], vzn_z[2], vzn_z[3], vzn_z[4]);
        st_nt4(out + 2 * VOL + cz, oxx[0], oxx[1], oxx[2], oxx[3]);
        st_nt4(out + 3 * VOL + cz, ozz[0], ozz[1], ozz[2], ozz[3]);
        st_nt4(out + 4 * VOL + cz, oxz[0], oxz[1], oxz[2], oxz[3]);
    }
}

extern "C" void kernel_launch(void* const* d_in, const int* in_sizes, int n_in,
                              void* d_out, int out_size, void* d_ws, size_t ws_size,
                              hipStream_t stream) {
    const float* vp  = (const float*)d_in[0];
    const float* vs  = (const float*)d_in[1];
    const float* rho = (const float*)d_in[2];
    const float* vx  = (const float*)d_in[3];
    const float* vz  = (const float*)d_in[4];
    const float* txx = (const float*)d_in[5];
    const float* tzz = (const float*)d_in[6];
    const float* txz = (const float*)d_in[7];
    const float* dd  = (const float*)d_in[8];
    float* out = (float*)d_out;

    const int threads = 256;
    const int blocks  = NBLK;  // 4096, exact
    hipLaunchKernelGGL(wave_fused_v3, dim3(blocks), dim3(threads), 0, stream,
                       vp, vs, rho, vx, vz, txx, tzz, txz, dd, out);
}

// Round 4
// 614.456 us; speedup vs baseline: 1.0806x; 1.0806x over previous
//
#include <hip/hip_runtime.h>

// WaveCell v4: 2D staggered-grid elastic FDTD timestep, fused single kernel.
// B=4, NZ=NX=2048, fp32, periodic wrap (pow2 dims).
//
// History:
//  v2 (212us dispatch): unroll 1, no swizzle. BW 3.85 TB/s, FETCH 470MB.
//  v3 (253us dispatch): +XCD swizzle +unroll 2. FETCH 210MB (swizzle works:
//      halo/L3 reuse captured) but time REGRESSED -> not HBM-volume bound;
//      unroll-2 scheduling (VGPR 68->76, waitcnt structure) is prime suspect.
//  v4: decouple — keep swizzle, revert shot loop to unroll 1 (v2 body).
//      Pre-committed read: dur<=212 -> unroll2 was the cost; dur~253 ->
//      swizzle itself costs time, revert it next.

constexpr int NZ = 2048;
constexpr int NX = 2048;
constexpr int B  = 4;
constexpr int PLANE = NZ * NX;      // 4,194,304
constexpr int VOL   = B * PLANE;    // 16,777,216
constexpr float DT    = 1e-3f;
constexpr float INV_H = 0.1f;       // 1/10m
constexpr int NBLK  = (PLANE / 4) / 256;   // 4096
constexpr int NXCD  = 8;
constexpr int BLK_PER_XCD = NBLK / NXCD;   // 512

typedef float f32x4 __attribute__((ext_vector_type(4)));

__device__ __forceinline__ float rcpf(float x) { return __builtin_amdgcn_rcpf(x); }
__device__ __forceinline__ float4 ld4(const float* __restrict__ p) {
    return *reinterpret_cast<const float4*>(p);
}
__device__ __forceinline__ void st_nt4(float* __restrict__ p,
                                       float a, float b, float c, float d) {
    f32x4 v = {a, b, c, d};
    __builtin_nontemporal_store(v, reinterpret_cast<f32x4*>(p));
}

__global__ __launch_bounds__(256) void wave_fused_v4(
    const float* __restrict__ vp,  const float* __restrict__ vs,
    const float* __restrict__ rho,
    const float* __restrict__ vx,  const float* __restrict__ vz,
    const float* __restrict__ txx, const float* __restrict__ tzz,
    const float* __restrict__ txz,
    const float* __restrict__ dd,
    float* __restrict__ out)
{
    // XCD-band swizzle: consecutive hardware dispatch slots round-robin the
    // 8 XCDs; give XCD k the contiguous block range [k*512, (k+1)*512) so
    // each XCD streams a contiguous 256-row z-band through its private L2.
    const int bid = blockIdx.x;
    const int sb  = (bid & (NXCD - 1)) * BLK_PER_XCD + (bid >> 3);
    const int t   = sb * blockDim.x + threadIdx.x;          // [0, PLANE/4)
    const int xg = (t & (NX / 4 - 1)) << 2;                 // x base, %4==0
    const int z  = t >> 9;                                  // t / (NX/4)
    const int zp = (z + 1) & (NZ - 1);
    const int zm = (z - 1) & (NZ - 1);
    const int xm1 = (xg - 1) & (NX - 1);
    const int xp4 = (xg + 4) & (NX - 1);
    const int rz  = z  * NX;
    const int rzp = zp * NX;
    const int rzm = zm * NX;

    // ---------- 2D coefficient setup (amortized over B=4 shots) ----------
    float dz6[6], rz6[6];
    {
        const float4 d4 = ld4(dd + rz + xg);
        dz6[0] = dd[rz + xm1]; dz6[1] = d4.x; dz6[2] = d4.y;
        dz6[3] = d4.z;         dz6[4] = d4.w; dz6[5] = dd[rz + xp4];
        const float4 r4 = ld4(rho + rz + xg);
        rz6[0] = rho[rz + xm1]; rz6[1] = r4.x; rz6[2] = r4.y;
        rz6[3] = r4.z;          rz6[4] = r4.w; rz6[5] = rho[rz + xp4];
    }
    float avz[6], bvz[6], inv_c[4];
    #pragma unroll
    for (int j = 0; j < 6; ++j) {
        const float c   = 0.5f * DT * dz6[j];
        const float inv = rcpf(1.0f + c);
        avz[j] = (1.0f - c) * inv;
        bvz[j] = DT * INV_H * inv * rcpf(rz6[j]);
        if (j >= 1 && j <= 4) inv_c[j - 1] = inv;   // static after unroll
    }
    float avzp[4], bvzp[4], avzm[4], bvzm[4];
    {
        const float4 dp = ld4(dd + rzp + xg), dm = ld4(dd + rzm + xg);
        const float4 rp = ld4(rho + rzp + xg), rm = ld4(rho + rzm + xg);
        const float dpa[4] = {dp.x, dp.y, dp.z, dp.w};
        const float dma[4] = {dm.x, dm.y, dm.z, dm.w};
        const float rpa[4] = {rp.x, rp.y, rp.z, rp.w};
        const float rma[4] = {rm.x, rm.y, rm.z, rm.w};
        #pragma unroll
        for (int k = 0; k < 4; ++k) {
            float c = 0.5f * DT * dpa[k];
            float inv = rcpf(1.0f + c);
            avzp[k] = (1.0f - c) * inv;
            bvzp[k] = DT * INV_H * inv * rcpf(rpa[k]);
            c = 0.5f * DT * dma[k];
            inv = rcpf(1.0f + c);
            avzm[k] = (1.0f - c) * inv;
            bvzm[k] = DT * INV_H * inv * rcpf(rma[k]);
        }
    }
    float q1[4], q2[4], q3[4], a_s[4];
    {
        const float4 vp4 = ld4(vp + rz + xg), vs4 = ld4(vs + rz + xg);
        const float vpa[4] = {vp4.x, vp4.y, vp4.z, vp4.w};
        const float vsa[4] = {vs4.x, vs4.y, vs4.z, vs4.w};
        #pragma unroll
        for (int k = 0; k < 4; ++k) {
            const float r   = rz6[k + 1];
            const float muv = r * vsa[k] * vsa[k];
            const float lam = r * vpa[k] * vpa[k] - 2.0f * muv;
            const float bsH = DT * INV_H * inv_c[k];
            q1[k] = bsH * (lam + 2.0f * muv);
            q2[k] = bsH * lam;
            q3[k] = bsH * muv;
            a_s[k] = avz[k + 1];
        }
    }

    // ---------- per-shot field update ----------
    #pragma unroll 1   // v2 scheduling: per-shot burst of 26 loads, one drain
    for (int b = 0; b < B; ++b) {
        const int b3  = b * PLANE;
        const int cz  = b3 + rz  + xg;
        const int czp = b3 + rzp + xg;
        const int czm = b3 + rzm + xg;

        // row segments (array index j <-> column xg-1+j unless noted)
        float txxz[6], txzz[6], tzzz[5], tzzzp[5], txxzp[5];
        float txzzm[5];                 // index k <-> column xg+k
        float vxz[5];                   // index k <-> column xg+k
        float vzz[5];                   // index j <-> column xg-1+j
        {
            float4 m;
            m = ld4(txx + cz);
            txxz[1] = m.x; txxz[2] = m.y; txxz[3] = m.z; txxz[4] = m.w;
            txxz[0] = txx[b3 + rz + xm1];  txxz[5] = txx[b3 + rz + xp4];
            m = ld4(txz + cz);
            txzz[1] = m.x; txzz[2] = m.y; txzz[3] = m.z; txzz[4] = m.w;
            txzz[0] = txz[b3 + rz + xm1];  txzz[5] = txz[b3 + rz + xp4];
            m = ld4(tzz + cz);
            tzzz[1] = m.x; tzzz[2] = m.y; tzzz[3] = m.z; tzzz[4] = m.w;
            tzzz[0] = tzz[b3 + rz + xm1];
            m = ld4(tzz + czp);
            tzzzp[1] = m.x; tzzzp[2] = m.y; tzzzp[3] = m.z; tzzzp[4] = m.w;
            tzzzp[0] = tzz[b3 + rzp + xm1];
            m = ld4(txx + czp);
            txxzp[1] = m.x; txxzp[2] = m.y; txxzp[3] = m.z; txxzp[4] = m.w;
            txxzp[0] = txx[b3 + rzp + xm1];
            m = ld4(txz + czm);
            txzzm[0] = m.x; txzzm[1] = m.y; txzzm[2] = m.z; txzzm[3] = m.w;
            txzzm[4] = txz[b3 + rzm + xp4];
            m = ld4(vx + cz);
            vxz[0] = m.x; vxz[1] = m.y; vxz[2] = m.z; vxz[3] = m.w;
            vxz[4] = vx[b3 + rz + xp4];
            m = ld4(vz + cz);
            vzz[1] = m.x; vzz[2] = m.y; vzz[3] = m.z; vzz[4] = m.w;
            vzz[0] = vz[b3 + rz + xm1];
        }
        const float4 tp4 = ld4(txz + czp);   // txz row zp, cols xg..xg+3
        const float4 tm4 = ld4(tzz + czm);   // tzz row zm, cols xg..xg+3
        const float4 vxp4 = ld4(vx + czp);   // vx  row zp, cols xg..xg+3
        const float4 vzm4 = ld4(vz + czm);   // vz  row zm, cols xg..xg+3
        const float txzzp[4] = {tp4.x, tp4.y, tp4.z, tp4.w};
        const float tzzzm[4] = {tm4.x, tm4.y, tm4.z, tm4.w};
        const float vxzp[4]  = {vxp4.x, vxp4.y, vxp4.z, vxp4.w};
        const float vzzm[4]  = {vzm4.x, vzm4.y, vzm4.z, vzm4.w};

        // --- new velocities (leapfrog: from old stresses) ---
        float vxn_z[5];                 // vx_new(z, xg+k), k=0..4
        #pragma unroll
        for (int k = 0; k < 5; ++k)
            vxn_z[k] = avz[k + 1] * vxz[k]
                     + bvz[k + 1] * ((txxz[k + 1] - txxz[k])
                                   + (txzz[k + 1] - txzzm[k]));
        float vzn_z[5];                 // vz_new(z, xg-1+k), k=0..4
        #pragma unroll
        for (int k = 0; k < 5; ++k)
            vzn_z[k] = avz[k] * vzz[k]
                     + bvz[k] * ((txzz[k + 1] - txzz[k])
                               + (tzzzp[k] - tzzz[k]));
        float vxn_zp[4];                // vx_new(zp, xg+k)
        #pragma unroll
        for (int k = 0; k < 4; ++k)
            vxn_zp[k] = avzp[k] * vxzp[k]
                      + bvzp[k] * ((txxzp[k + 1] - txxzp[k])
                                 + (txzzp[k] - txzz[k + 1]));
        float vzn_zm[4];                // vz_new(zm, xg+k)
        #pragma unroll
        for (int k = 0; k < 4; ++k)
            vzn_zm[k] = avzm[k] * vzzm[k]
                      + bvzm[k] * ((txzzm[k + 1] - txzzm[k])
                                 + (tzzz[k + 1] - tzzzm[k]));

        // --- stress update (from new velocities) ---
        float oxx[4], ozz[4], oxz[4];
        #pragma unroll
        for (int k = 0; k < 4; ++k) {
            const float dvx = vxn_z[k + 1] - vxn_z[k];          // d+x vx_new
            const float dvz = vzn_z[k + 1] - vzn_zm[k];         // d-z vz_new
            oxx[k] = a_s[k] * txxz[k + 1] + q1[k] * dvx + q2[k] * dvz;
            ozz[k] = a_s[k] * tzzz[k + 1] + q1[k] * dvz + q2[k] * dvx;
            oxz[k] = a_s[k] * txzz[k + 1]
                   + q3[k] * ((vxn_zp[k] - vxn_z[k])
                            + (vzn_z[k + 1] - vzn_z[k]));
        }

        st_nt4(out + 0 * VOL + cz, vxn_z[0], vxn_z[1], vxn_z[2], vxn_z[3]);
        st_nt4(out + 1 * VOL + cz, vzn_z[1], vzn_z[2], vzn_z[3], vzn_z[4]);
        st_nt4(out + 2 * VOL + cz, oxx[0], oxx[1], oxx[2], oxx[3]);
        st_nt4(out + 3 * VOL + cz, ozz[0], ozz[1], ozz[2], ozz[3]);
        st_nt4(out + 4 * VOL + cz, oxz[0], oxz[1], oxz[2], oxz[3]);
    }
}

extern "C" void kernel_launch(void* const* d_in, const int* in_sizes, int n_in,
                              void* d_out, int out_size, void* d_ws, size_t ws_size,
                              hipStream_t stream) {
    const float* vp  = (const float*)d_in[0];
    const float* vs  = (const float*)d_in[1];
    const float* rho = (const float*)d_in[2];
    const float* vx  = (const float*)d_in[3];
    const float* vz  = (const float*)d_in[4];
    const float* txx = (const float*)d_in[5];
    const float* tzz = (const float*)d_in[6];
    const float* txz = (const float*)d_in[7];
    const float* dd  = (const float*)d_in[8];
    float* out = (float*)d_out;

    const int threads = 256;
    const int blocks  = NBLK;  // 4096, exact
    hipLaunchKernelGGL(wave_fused_v4, dim3(blocks), dim3(threads), 0, stream,
                       vp, vs, rho, vx, vz, txx, tzz, txz, dd, out);
}